// Round 10
// baseline (38.759 us; speedup 1.0000x reference)
//
#include <hip/hip_runtime.h>

// ResiduePose: coords[b,l,a,:] = R(q/|q|) · P[a] + (t[b,l] - mean_l t[b])
// B=32, L=65536, f32.
//   stage 1: 512 blocks x 512 threads: partial sums over trans (2 groups/thread)
//            + L3-warm prefetch of quat (8 f32x4/thread, kept live via asm).
//            Makes stage1 the single read-only pass over ALL inputs.
//   stage 2: pose, now write-mostly (quat hits L3): 16-partial mean in 3 lanes,
//            LDS-staged trans + output, NT coalesced stores.

#define BB 32
#define LL 65536
#define S1_BLOCKS 512                     // 16 per batch
#define S1_TPB 512
#define S1_GROUPS_PER_BLOCK 1024          // (BB*LL/4) / 512
#define RES_PER_S1_BLOCK 4096             // groups*4
#define RES_PER_BLOCK 256
#define POSE_BLOCKS ((BB * LL) / RES_PER_BLOCK)   // 8192
#define PPB 16                            // partials per batch

typedef float f32x4 __attribute__((ext_vector_type(4)));

// ---------------- stage 1: partial sums + quat L3 warm ----------------
__global__ __launch_bounds__(S1_TPB) void partial_sums_kernel(
    const f32x4* __restrict__ trans4, const f32x4* __restrict__ quat4,
    float* __restrict__ partials) {
    const int bid = blockIdx.x;
    const int tid = threadIdx.x;

    float s0 = 0.f, s1 = 0.f, s2 = 0.f;
#pragma unroll
    for (int it = 0; it < 2; ++it) {
        // group = 4 residues = 3 f32x4 = 48 B
        const size_t m = ((size_t)bid * S1_GROUPS_PER_BLOCK + it * S1_TPB + tid) * 3;
        const f32x4 a = trans4[m + 0];   // x0 y0 z0 x1
        const f32x4 c = trans4[m + 1];   // y1 z1 x2 y2
        const f32x4 d = trans4[m + 2];   // z2 x3 y3 z3
        s0 += a.x + a.w + c.z + d.y;
        s1 += a.y + c.x + c.w + d.z;
        s2 += a.z + c.y + d.x + d.w;
    }

    // quat L3-warm prefetch: 8 f32x4/thread covering this block's 4096 residues.
    // Values unused; keep loads live (rule: ablation-via-skip DCEs ops).
    {
        const size_t qb = (size_t)bid * RES_PER_S1_BLOCK;
        float acc = 0.f;
#pragma unroll
        for (int it = 0; it < 8; ++it) {
            const f32x4 qv = quat4[qb + it * S1_TPB + tid];
            acc += qv.x + qv.y + qv.z + qv.w;
        }
        asm volatile("" :: "v"(acc));    // keep-alive, zero semantic effect
    }

#pragma unroll
    for (int off = 32; off > 0; off >>= 1) {
        s0 += __shfl_down(s0, off);
        s1 += __shfl_down(s1, off);
        s2 += __shfl_down(s2, off);
    }
    __shared__ float red[8][3];
    const int wave = tid >> 6;
    if ((tid & 63) == 0) { red[wave][0] = s0; red[wave][1] = s1; red[wave][2] = s2; }
    __syncthreads();
    if (tid < 3) {
        float s = 0.f;
#pragma unroll
        for (int w = 0; w < 8; ++w) s += red[w][tid];
        partials[bid * 3 + tid] = s;      // layout [b][16][3]
    }
}

// ---------------- stage 2: pose, LDS-staged I/O, NT stores ----------------
__global__ __launch_bounds__(256) void pose_kernel(
    const f32x4* __restrict__ trans4, const f32x4* __restrict__ quat4,
    const float* __restrict__ partials, f32x4* __restrict__ out4) {
    __shared__ f32x4 stage[768];     // 12 KB: trans staging, then output staging
    __shared__ float mean[3];

    const int tid = threadIdx.x;
    const int b = blockIdx.x >> 8;                      // 256 pose-blocks per batch
    const size_t r0 = (size_t)blockIdx.x * RES_PER_BLOCK;

    const f32x4 q4 = quat4[r0 + tid];                   // L3-hit after stage1 warm
    if (tid < 192) stage[tid] = trans4[(size_t)blockIdx.x * 192 + tid];
    if (tid < 3) {                                      // 16 independent L2-hit loads
        float s = 0.f;
#pragma unroll
        for (int p = 0; p < PPB; ++p) s += partials[(b * PPB + p) * 3 + tid];
        mean[tid] = s * (1.0f / (float)LL);
    }
    __syncthreads();

    const float mx = mean[0], my = mean[1], mz = mean[2];
    const float* sf = (const float*)stage;              // stride-3 LDS reads: free
    const float tx = sf[tid * 3 + 0] - mx;
    const float ty = sf[tid * 3 + 1] - my;
    const float tz = sf[tid * 3 + 2] - mz;

    float r = q4.x, i = q4.y, j = q4.z, k = q4.w;
    const float inv = 1.0f / (sqrtf(r * r + i * i + j * j + k * k) + 1e-6f);
    r *= inv; i *= inv; j *= inv; k *= inv;

    const float R00 = 1.f - 2.f * (j * j + k * k);
    const float R01 = 2.f * (i * j - k * r);
    const float R02 = 2.f * (i * k + j * r);
    const float R10 = 2.f * (i * j + k * r);
    const float R11 = 1.f - 2.f * (i * i + k * k);
    const float R12 = 2.f * (j * k - i * r);
    const float R20 = 2.f * (i * k - j * r);
    const float R21 = 2.f * (j * k + i * r);
    const float R22 = 1.f - 2.f * (i * i + j * j);

    // idealized internal coords (N, CA=origin, C, CB)
    const float Nx = 1.460091f;
    const float Cx = -0.56431316f, Cy = 1.41695817f;
    const float Bx = -0.52426314f, By = -0.76611338f, Bz = 1.20561194f;

    const float N0 = R00 * Nx + tx, N1 = R10 * Nx + ty, N2 = R20 * Nx + tz;
    const float C0 = R00 * Cx + R01 * Cy + tx;
    const float C1 = R10 * Cx + R11 * Cy + ty;
    const float C2 = R20 * Cx + R21 * Cy + tz;
    const float B0 = R00 * Bx + R01 * By + R02 * Bz + tx;
    const float B1 = R10 * Bx + R11 * By + R12 * Bz + ty;
    const float B2 = R20 * Bx + R21 * By + R22 * Bz + tz;

    __syncthreads();   // done reading trans staging
    stage[tid * 3 + 0] = (f32x4){N0, N1, N2, tx};
    stage[tid * 3 + 1] = (f32x4){ty, tz, C0, C1};
    stage[tid * 3 + 2] = (f32x4){C2, B0, B1, B2};
    __syncthreads();

    // 3 lane-contiguous nontemporal f32x4 stores
    const size_t ob = r0 * 3;
    __builtin_nontemporal_store(stage[0 * 256 + tid], &out4[ob + 0 * 256 + tid]);
    __builtin_nontemporal_store(stage[1 * 256 + tid], &out4[ob + 1 * 256 + tid]);
    __builtin_nontemporal_store(stage[2 * 256 + tid], &out4[ob + 2 * 256 + tid]);
}

extern "C" void kernel_launch(void* const* d_in, const int* in_sizes, int n_in,
                              void* d_out, int out_size, void* d_ws, size_t ws_size,
                              hipStream_t stream) {
    const f32x4* trans4 = (const f32x4*)d_in[0];   // (B,L,3) f32
    const f32x4* quat4 = (const f32x4*)d_in[1];    // (B,L,4) f32
    f32x4* out4 = (f32x4*)d_out;                   // (B,L,4,3) f32

    float* partials = (float*)d_ws;                // S1_BLOCKS*3 = 1536 floats

    partial_sums_kernel<<<S1_BLOCKS, S1_TPB, 0, stream>>>(trans4, quat4, partials);
    pose_kernel<<<POSE_BLOCKS, 256, 0, stream>>>(trans4, quat4, partials, out4);
}

// Round 11
// 38.716 us; speedup vs baseline: 1.0011x; 1.0011x over previous
//
#include <hip/hip_runtime.h>

// ResiduePose: coords[b,l,a,:] = R(q/|q|) · P[a] + (t[b,l] - mean_l t[b])
// B=32, L=65536, f32.
//   stage 1: 512 blocks x 512 threads, partial sums over trans, 16 partials/batch.
//   stage 2: pose with FAT blocks (1024 thr, 1024 residues, 2048 blocks) to
//            amortize per-block head/tail latency; LDS-staged trans + output,
//            NT coalesced stores. (r10's quat-warm reverted: -4.9 us regression,
//            proved marginal bytes cost full HBM time.)

#define BB 32
#define LL 65536
#define S1_BLOCKS 512                     // 16 per batch
#define S1_TPB 512
#define S1_GROUPS_PER_BLOCK 1024          // (BB*LL/4) / 512
#define PPB 16                            // partials per batch

#define P_TPB 1024
#define RES_PER_BLOCK 1024
#define POSE_BLOCKS ((BB * LL) / RES_PER_BLOCK)   // 2048

typedef float f32x4 __attribute__((ext_vector_type(4)));

// ---------------- stage 1: partial sums, 512 x 512 ----------------
__global__ __launch_bounds__(S1_TPB) void partial_sums_kernel(
    const f32x4* __restrict__ trans4, float* __restrict__ partials) {
    const int bid = blockIdx.x;
    const int tid = threadIdx.x;

    float s0 = 0.f, s1 = 0.f, s2 = 0.f;
#pragma unroll
    for (int it = 0; it < 2; ++it) {
        // group = 4 residues = 3 f32x4 = 48 B
        const size_t m = ((size_t)bid * S1_GROUPS_PER_BLOCK + it * S1_TPB + tid) * 3;
        const f32x4 a = trans4[m + 0];   // x0 y0 z0 x1
        const f32x4 c = trans4[m + 1];   // y1 z1 x2 y2
        const f32x4 d = trans4[m + 2];   // z2 x3 y3 z3
        s0 += a.x + a.w + c.z + d.y;
        s1 += a.y + c.x + c.w + d.z;
        s2 += a.z + c.y + d.x + d.w;
    }

#pragma unroll
    for (int off = 32; off > 0; off >>= 1) {
        s0 += __shfl_down(s0, off);
        s1 += __shfl_down(s1, off);
        s2 += __shfl_down(s2, off);
    }
    __shared__ float red[8][3];
    const int wave = tid >> 6;
    if ((tid & 63) == 0) { red[wave][0] = s0; red[wave][1] = s1; red[wave][2] = s2; }
    __syncthreads();
    if (tid < 3) {
        float s = 0.f;
#pragma unroll
        for (int w = 0; w < 8; ++w) s += red[w][tid];
        partials[bid * 3 + tid] = s;      // layout [b][16][3]
    }
}

// ---------------- stage 2: pose, 1024-residue blocks, LDS-staged I/O ----------------
__global__ __launch_bounds__(P_TPB) void pose_kernel(
    const f32x4* __restrict__ trans4, const f32x4* __restrict__ quat4,
    const float* __restrict__ partials, f32x4* __restrict__ out4) {
    __shared__ f32x4 stage[RES_PER_BLOCK * 3];   // 48 KB; trans in first 12 KB, then output
    __shared__ float mean[3];

    const int tid = threadIdx.x;
    const int b = blockIdx.x >> 6;                      // 64 pose-blocks per batch
    const size_t r0 = (size_t)blockIdx.x * RES_PER_BLOCK;

    const f32x4 q4 = quat4[r0 + tid];                   // perfect 16B/lane coalescing
    if (tid < RES_PER_BLOCK * 3 / 4)                    // 768 f32x4 trans staging
        stage[tid] = trans4[(size_t)blockIdx.x * (RES_PER_BLOCK * 3 / 4) + tid];
    if (tid < 3) {                                      // 16 independent L2-hit loads
        float s = 0.f;
#pragma unroll
        for (int p = 0; p < PPB; ++p) s += partials[(b * PPB + p) * 3 + tid];
        mean[tid] = s * (1.0f / (float)LL);
    }
    __syncthreads();

    const float mx = mean[0], my = mean[1], mz = mean[2];
    const float* sf = (const float*)stage;              // stride-3 LDS reads: free
    const float tx = sf[tid * 3 + 0] - mx;
    const float ty = sf[tid * 3 + 1] - my;
    const float tz = sf[tid * 3 + 2] - mz;

    float r = q4.x, i = q4.y, j = q4.z, k = q4.w;
    const float inv = 1.0f / (sqrtf(r * r + i * i + j * j + k * k) + 1e-6f);
    r *= inv; i *= inv; j *= inv; k *= inv;

    const float R00 = 1.f - 2.f * (j * j + k * k);
    const float R01 = 2.f * (i * j - k * r);
    const float R02 = 2.f * (i * k + j * r);
    const float R10 = 2.f * (i * j + k * r);
    const float R11 = 1.f - 2.f * (i * i + k * k);
    const float R12 = 2.f * (j * k - i * r);
    const float R20 = 2.f * (i * k - j * r);
    const float R21 = 2.f * (j * k + i * r);
    const float R22 = 1.f - 2.f * (i * i + j * j);

    // idealized internal coords (N, CA=origin, C, CB)
    const float Nx = 1.460091f;
    const float Cx = -0.56431316f, Cy = 1.41695817f;
    const float Bx = -0.52426314f, By = -0.76611338f, Bz = 1.20561194f;

    const float N0 = R00 * Nx + tx, N1 = R10 * Nx + ty, N2 = R20 * Nx + tz;
    const float C0 = R00 * Cx + R01 * Cy + tx;
    const float C1 = R10 * Cx + R11 * Cy + ty;
    const float C2 = R20 * Cx + R21 * Cy + tz;
    const float B0 = R00 * Bx + R01 * By + R02 * Bz + tx;
    const float B1 = R10 * Bx + R11 * By + R12 * Bz + ty;
    const float B2 = R20 * Bx + R21 * By + R22 * Bz + tz;

    __syncthreads();   // done reading trans staging
    stage[tid * 3 + 0] = (f32x4){N0, N1, N2, tx};
    stage[tid * 3 + 1] = (f32x4){ty, tz, C0, C1};
    stage[tid * 3 + 2] = (f32x4){C2, B0, B1, B2};
    __syncthreads();

    // 3 lane-contiguous nontemporal f32x4 stores across 1024 lanes
    const size_t ob = r0 * 3;
    __builtin_nontemporal_store(stage[0 * P_TPB + tid], &out4[ob + 0 * P_TPB + tid]);
    __builtin_nontemporal_store(stage[1 * P_TPB + tid], &out4[ob + 1 * P_TPB + tid]);
    __builtin_nontemporal_store(stage[2 * P_TPB + tid], &out4[ob + 2 * P_TPB + tid]);
}

extern "C" void kernel_launch(void* const* d_in, const int* in_sizes, int n_in,
                              void* d_out, int out_size, void* d_ws, size_t ws_size,
                              hipStream_t stream) {
    const f32x4* trans4 = (const f32x4*)d_in[0];   // (B,L,3) f32
    const f32x4* quat4 = (const f32x4*)d_in[1];    // (B,L,4) f32
    f32x4* out4 = (f32x4*)d_out;                   // (B,L,4,3) f32

    float* partials = (float*)d_ws;                // S1_BLOCKS*3 = 1536 floats

    partial_sums_kernel<<<S1_BLOCKS, S1_TPB, 0, stream>>>(trans4, partials);
    pose_kernel<<<POSE_BLOCKS, P_TPB, 0, stream>>>(trans4, quat4, partials, out4);
}

// Round 12
// 33.896 us; speedup vs baseline: 1.1435x; 1.1422x over previous
//
#include <hip/hip_runtime.h>

// ResiduePose: coords[b,l,a,:] = R(q/|q|) · P[a] + (t[b,l] - mean_l t[b])
// B=32, L=65536, f32.
//   stage 1: 512 blocks x 512 threads, partial sums over trans, 16 partials/batch.
//   stage 2: pose, SINGLE-GENERATION grid: 2048 blocks x 256 thr (8/CU by 18 KB
//            LDS, full 32-wave occupancy, exactly one wavefront of blocks).
//            Each block: 4 chunks of 256 residues, software-pipelined (issue
//            next chunk's global loads before computing current), double-
//            buffered trans LDS, LDS-staged output -> NT coalesced stores.

#define BB 32
#define LL 65536
#define S1_BLOCKS 512                     // 16 per batch
#define S1_TPB 512
#define S1_GROUPS_PER_BLOCK 1024          // (BB*LL/4) / 512
#define PPB 16                            // partials per batch

#define P_TPB 256
#define CHUNKS 4
#define RES_PER_POSE_BLOCK 1024
#define POSE_BLOCKS ((BB * LL) / RES_PER_POSE_BLOCK)   // 2048

typedef float f32x4 __attribute__((ext_vector_type(4)));

// ---------------- stage 1: partial sums, 512 x 512 ----------------
__global__ __launch_bounds__(S1_TPB) void partial_sums_kernel(
    const f32x4* __restrict__ trans4, float* __restrict__ partials) {
    const int bid = blockIdx.x;
    const int tid = threadIdx.x;

    float s0 = 0.f, s1 = 0.f, s2 = 0.f;
#pragma unroll
    for (int it = 0; it < 2; ++it) {
        const size_t m = ((size_t)bid * S1_GROUPS_PER_BLOCK + it * S1_TPB + tid) * 3;
        const f32x4 a = trans4[m + 0];   // x0 y0 z0 x1
        const f32x4 c = trans4[m + 1];   // y1 z1 x2 y2
        const f32x4 d = trans4[m + 2];   // z2 x3 y3 z3
        s0 += a.x + a.w + c.z + d.y;
        s1 += a.y + c.x + c.w + d.z;
        s2 += a.z + c.y + d.x + d.w;
    }

#pragma unroll
    for (int off = 32; off > 0; off >>= 1) {
        s0 += __shfl_down(s0, off);
        s1 += __shfl_down(s1, off);
        s2 += __shfl_down(s2, off);
    }
    __shared__ float red[8][3];
    const int wave = tid >> 6;
    if ((tid & 63) == 0) { red[wave][0] = s0; red[wave][1] = s1; red[wave][2] = s2; }
    __syncthreads();
    if (tid < 3) {
        float s = 0.f;
#pragma unroll
        for (int w = 0; w < 8; ++w) s += red[w][tid];
        partials[bid * 3 + tid] = s;      // layout [b][16][3]
    }
}

// ---------------- stage 2: pose, single-generation pipelined blocks ----------------
__global__ __launch_bounds__(P_TPB) void pose_kernel(
    const f32x4* __restrict__ trans4, const f32x4* __restrict__ quat4,
    const float* __restrict__ partials, f32x4* __restrict__ out4) {
    __shared__ f32x4 strans[2][192];   // 6 KB double-buffered trans staging
    __shared__ f32x4 sout[768];        // 12 KB output staging
    __shared__ float mean[3];

    const int tid = threadIdx.x;
    const int bid = blockIdx.x;
    const int b = bid >> 6;                              // 64 pose-blocks per batch
    const size_t r0 = (size_t)bid * RES_PER_POSE_BLOCK;  // first residue
    const size_t tbase = (size_t)bid * (RES_PER_POSE_BLOCK * 3 / 4);  // f32x4

    // prologue: chunk-0 loads + mean gather
    f32x4 qv = quat4[r0 + tid];
    if (tid < 192) strans[0][tid] = trans4[tbase + tid];
    if (tid < 3) {
        float s = 0.f;
#pragma unroll
        for (int p = 0; p < PPB; ++p) s += partials[(b * PPB + p) * 3 + tid];
        mean[tid] = s * (1.0f / (float)LL);
    }
    __syncthreads();
    const float mx = mean[0], my = mean[1], mz = mean[2];

    // idealized internal coords (N, CA=origin, C, CB)
    const float Nx = 1.460091f;
    const float Cx = -0.56431316f, Cy = 1.41695817f;
    const float Bx = -0.52426314f, By = -0.76611338f, Bz = 1.20561194f;

    f32x4 qn, tn;
#pragma unroll
    for (int ch = 0; ch < CHUNKS; ++ch) {
        // issue next chunk's global loads early (in flight across compute+store)
        if (ch < CHUNKS - 1) {
            qn = quat4[r0 + (ch + 1) * P_TPB + tid];
            if (tid < 192) tn = trans4[tbase + (ch + 1) * 192 + tid];
        }

        const float* sf = (const float*)strans[ch & 1];  // stride-3 LDS reads: free
        const float tx = sf[tid * 3 + 0] - mx;
        const float ty = sf[tid * 3 + 1] - my;
        const float tz = sf[tid * 3 + 2] - mz;

        float r = qv.x, i = qv.y, j = qv.z, k = qv.w;
        const float inv = 1.0f / (sqrtf(r * r + i * i + j * j + k * k) + 1e-6f);
        r *= inv; i *= inv; j *= inv; k *= inv;

        const float R00 = 1.f - 2.f * (j * j + k * k);
        const float R01 = 2.f * (i * j - k * r);
        const float R02 = 2.f * (i * k + j * r);
        const float R10 = 2.f * (i * j + k * r);
        const float R11 = 1.f - 2.f * (i * i + k * k);
        const float R12 = 2.f * (j * k - i * r);
        const float R20 = 2.f * (i * k - j * r);
        const float R21 = 2.f * (j * k + i * r);
        const float R22 = 1.f - 2.f * (i * i + j * j);

        const float N0 = R00 * Nx + tx, N1 = R10 * Nx + ty, N2 = R20 * Nx + tz;
        const float C0 = R00 * Cx + R01 * Cy + tx;
        const float C1 = R10 * Cx + R11 * Cy + ty;
        const float C2 = R20 * Cx + R21 * Cy + tz;
        const float B0 = R00 * Bx + R01 * By + R02 * Bz + tx;
        const float B1 = R10 * Bx + R11 * By + R12 * Bz + ty;
        const float B2 = R20 * Bx + R21 * By + R22 * Bz + tz;

        sout[tid * 3 + 0] = (f32x4){N0, N1, N2, tx};
        sout[tid * 3 + 1] = (f32x4){ty, tz, C0, C1};
        sout[tid * 3 + 2] = (f32x4){C2, B0, B1, B2};
        __syncthreads();

        // 3 lane-contiguous nontemporal f32x4 stores for this chunk
        const size_t ob = (size_t)bid * (RES_PER_POSE_BLOCK * 3) + (size_t)ch * 768;
        __builtin_nontemporal_store(sout[0 * P_TPB + tid], &out4[ob + 0 * P_TPB + tid]);
        __builtin_nontemporal_store(sout[1 * P_TPB + tid], &out4[ob + 1 * P_TPB + tid]);
        __builtin_nontemporal_store(sout[2 * P_TPB + tid], &out4[ob + 2 * P_TPB + tid]);

        if (ch < CHUNKS - 1) {
            if (tid < 192) strans[(ch + 1) & 1][tid] = tn;
            qv = qn;
        }
        __syncthreads();   // sout consumed + next strans buffer ready
    }
}

extern "C" void kernel_launch(void* const* d_in, const int* in_sizes, int n_in,
                              void* d_out, int out_size, void* d_ws, size_t ws_size,
                              hipStream_t stream) {
    const f32x4* trans4 = (const f32x4*)d_in[0];   // (B,L,3) f32
    const f32x4* quat4 = (const f32x4*)d_in[1];    // (B,L,4) f32
    f32x4* out4 = (f32x4*)d_out;                   // (B,L,4,3) f32

    float* partials = (float*)d_ws;                // S1_BLOCKS*3 = 1536 floats

    partial_sums_kernel<<<S1_BLOCKS, S1_TPB, 0, stream>>>(trans4, partials);
    pose_kernel<<<POSE_BLOCKS, P_TPB, 0, stream>>>(trans4, quat4, partials, out4);
}